// Round 1
// baseline (133.445 us; speedup 1.0000x reference)
//
#include <hip/hip_runtime.h>

typedef float  f32x4  __attribute__((ext_vector_type(4)));
typedef __bf16 bf16x8 __attribute__((ext_vector_type(8)));
typedef __bf16 bf16x2 __attribute__((ext_vector_type(2)));

#define N_ 256
#define C_ 512
#define H_ 64

// ---------------------------------------------------------------------------
// Transpose (P, Q, 64) fp32  ->  (64, P, Q) bf16
// ---------------------------------------------------------------------------
__global__ __launch_bounds__(256) void k_transpose(const float* __restrict__ src,
                                                   __bf16* __restrict__ dst,
                                                   int P, int Q) {
  __shared__ float tile[64][65];
  const int p  = blockIdx.y;
  const int q0 = blockIdx.x * 64;
  const int t  = threadIdx.x;
  const float* s = src + ((size_t)p * Q + q0) * 64;
#pragma unroll
  for (int j = 0; j < 16; ++j) {
    const int qq = j * 4 + (t >> 6);
    const int hh = t & 63;
    tile[qq][hh] = s[qq * 64 + hh];
  }
  __syncthreads();
#pragma unroll
  for (int j = 0; j < 16; ++j) {
    const int hh = j * 4 + (t >> 6);
    const int qq = t & 63;
    dst[((size_t)hh * P + p) * Q + q0 + qq] = (__bf16)tile[qq][hh];
  }
}

// ---------------------------------------------------------------------------
// Batched NT GEMM: per h, C[256][512] = A[256][512] * B[512][512]^T  (bf16)
// 128x128 tile, 4 waves (2x2), BK=64, mfma_f32_16x16x32_bf16.
// LDS layout: [row][chunk] with chunk byte offset XOR ((row&7)<<4) swizzle.
// global_load_lds keeps LDS linear; global source pre-swizzled to match.
// Epilogue: writes bf16 C (H,N,C layout) + per-channel sum / sumsq atomics.
// If BN_A: A elements get y = relu(a_sc[k]*a + a_sh[k]) during reg-staging.
// ---------------------------------------------------------------------------
template <bool BN_A>
__global__ __launch_bounds__(256, 2) void k_gemm(
    const __bf16* __restrict__ A,   // (H, 256, 512)
    const __bf16* __restrict__ B,   // (H, 512, 512)
    __bf16* __restrict__ Co,        // (H, 256, 512)
    const float* __restrict__ a_sc, const float* __restrict__ a_sh,
    float* __restrict__ sum_out, float* __restrict__ sq_out) {
  const int h  = blockIdx.y;
  const int tm = blockIdx.x >> 2, tn = blockIdx.x & 3;
  const int m0 = tm * 128, n0 = tn * 128;
  const __bf16* Ah = A + ((size_t)h * N_ + m0) * C_;
  const __bf16* Bh = B + ((size_t)h * C_ + n0) * C_;
  __shared__ __bf16 As[128 * 64];
  __shared__ __bf16 Bs[128 * 64];
  const int tid  = threadIdx.x;
  const int lane = tid & 63, wid = tid >> 6;
  const int wr = wid >> 1, wc = wid & 1;

  f32x4 acc[4][4] = {};

  for (int kt = 0; kt < 8; ++kt) {
    __syncthreads();   // previous tile's compute done before overwrite
    {
      const int lrow = lane >> 3;          // 0..7
      const int swz  = (lane & 7) ^ lrow;  // pre-swizzled global chunk
#pragma unroll
      for (int i = 0; i < 4; ++i) {
        const int row = wid * 32 + i * 8 + lrow;
        const __bf16* gb = Bh + (size_t)row * C_ + kt * 64 + swz * 8;
        __builtin_amdgcn_global_load_lds(
            (const __attribute__((address_space(1))) void*)gb,
            (__attribute__((address_space(3))) void*)(Bs + (wid * 32 + i * 8) * 64),
            16, 0, 0);
        if (!BN_A) {
          const __bf16* ga = Ah + (size_t)row * C_ + kt * 64 + swz * 8;
          __builtin_amdgcn_global_load_lds(
              (const __attribute__((address_space(1))) void*)ga,
              (__attribute__((address_space(3))) void*)(As + (wid * 32 + i * 8) * 64),
              16, 0, 0);
        }
      }
    }
    if (BN_A) {
      // reg-stage A with fused BN1 + ReLU, swizzled ds_write
      const int lrow = tid >> 3;  // 0..31
      const int cch  = tid & 7;
#pragma unroll
      for (int i = 0; i < 4; ++i) {
        const int row = i * 32 + lrow;
        bf16x8 v = *reinterpret_cast<const bf16x8*>(Ah + (size_t)row * C_ + kt * 64 + cch * 8);
        const int cg = kt * 64 + cch * 8;
        f32x4 s0 = *reinterpret_cast<const f32x4*>(a_sc + cg);
        f32x4 s1 = *reinterpret_cast<const f32x4*>(a_sc + cg + 4);
        f32x4 h0 = *reinterpret_cast<const f32x4*>(a_sh + cg);
        f32x4 h1 = *reinterpret_cast<const f32x4*>(a_sh + cg + 4);
        bf16x8 y;
#pragma unroll
        for (int e = 0; e < 4; ++e) {
          y[e]     = (__bf16)fmaxf(0.f, fmaf((float)v[e],     s0[e], h0[e]));
          y[e + 4] = (__bf16)fmaxf(0.f, fmaf((float)v[e + 4], s1[e], h1[e]));
        }
        const int boff = row * 128 + ((cch * 16) ^ ((row & 7) << 4));
        *reinterpret_cast<bf16x8*>(reinterpret_cast<char*>(As) + boff) = y;
      }
    }
    __syncthreads();   // staging (vm + lgkm) drained by compiler before barrier

    const int fr = lane & 15, kc = lane >> 4;
#pragma unroll
    for (int kk = 0; kk < 2; ++kk) {
      bf16x8 af[4], bfr[4];
#pragma unroll
      for (int mf = 0; mf < 4; ++mf) {
        const int row  = wr * 64 + mf * 16 + fr;
        const int boff = row * 128 + ((kk * 64 + kc * 16) ^ ((row & 7) << 4));
        af[mf] = *reinterpret_cast<const bf16x8*>(reinterpret_cast<const char*>(As) + boff);
      }
#pragma unroll
      for (int nf = 0; nf < 4; ++nf) {
        const int row  = wc * 64 + nf * 16 + fr;
        const int boff = row * 128 + ((kk * 64 + kc * 16) ^ ((row & 7) << 4));
        bfr[nf] = *reinterpret_cast<const bf16x8*>(reinterpret_cast<const char*>(Bs) + boff);
      }
#pragma unroll
      for (int mf = 0; mf < 4; ++mf)
#pragma unroll
        for (int nf = 0; nf < 4; ++nf)
          acc[mf][nf] = __builtin_amdgcn_mfma_f32_16x16x32_bf16(af[mf], bfr[nf], acc[mf][nf], 0, 0, 0);
    }
  }

  // epilogue: C/D layout col=lane&15, row=(lane>>4)*4+j  (m89/m91-verified)
  const int fr = lane & 15;
  const int rq = (lane >> 4) * 4;
  __bf16* Ch = Co + (size_t)h * N_ * C_;
#pragma unroll
  for (int nf = 0; nf < 4; ++nf) {
    const int oc = n0 + wc * 64 + nf * 16 + fr;
    float s = 0.f, s2 = 0.f;
#pragma unroll
    for (int mf = 0; mf < 4; ++mf) {
      const int rb = m0 + wr * 64 + mf * 16 + rq;
      f32x4 v = acc[mf][nf];
#pragma unroll
      for (int j = 0; j < 4; ++j) {
        const float f = v[j];
        Ch[(size_t)(rb + j) * C_ + oc] = (__bf16)f;
        s += f;
        s2 += f * f;
      }
    }
    // lanes {c, c+16, c+32, c+48} share the same column
    s  += __shfl_xor(s, 16);  s  += __shfl_xor(s, 32);
    s2 += __shfl_xor(s2, 16); s2 += __shfl_xor(s2, 32);
    if (lane < 16) {
      atomicAdd(&sum_out[oc], s);
      atomicAdd(&sq_out[oc], s2);
    }
  }
}

// ---------------------------------------------------------------------------
// BN finalize: a = g*rsqrt(var+eps); c = b - mean*a
// ---------------------------------------------------------------------------
__global__ void k_bnfin(const float* __restrict__ sum, const float* __restrict__ sq,
                        const float* __restrict__ g, const float* __restrict__ b,
                        float* __restrict__ a_sc, float* __restrict__ a_sh,
                        float inv_cnt) {
  const int o = threadIdx.x;
  if (o < C_) {
    const float m    = sum[o] * inv_cnt;
    const float var  = fmaxf(0.f, sq[o] * inv_cnt - m * m);
    const float rstd = rsqrtf(var + 1e-5f);
    const float a    = g[o] * rstd;
    a_sc[o] = a;
    a_sh[o] = b[o] - m * a;
  }
}

// ---------------------------------------------------------------------------
// Final: out[n][o][h] = relu(a2[o]*t2[h][n][o] + c2[o] + x[n][o][h])
// LDS transpose (h <-> o) per (n, 64-o tile)
// ---------------------------------------------------------------------------
__global__ __launch_bounds__(256) void k_finalize(const __bf16* __restrict__ t2,
                                                  const float* __restrict__ x,
                                                  const float* __restrict__ a2,
                                                  const float* __restrict__ c2,
                                                  float* __restrict__ out) {
  __shared__ float tile[64][65];
  const int n  = blockIdx.y;
  const int o0 = blockIdx.x * 64;
  const int t  = threadIdx.x;
#pragma unroll
  for (int j = 0; j < 8; ++j) {
    const int hh = j * 8 + (t >> 5);
    const int ol = (t & 31) * 2;
    bf16x2 v = *reinterpret_cast<const bf16x2*>(t2 + ((size_t)hh * N_ + n) * C_ + o0 + ol);
    tile[hh][ol]     = (float)v[0];
    tile[hh][ol + 1] = (float)v[1];
  }
  __syncthreads();
  const int ol = t >> 2;
  const int hb = (t & 3) * 16;
  const int o  = o0 + ol;
  const float a = a2[o], c = c2[o];
  const float4* xp = reinterpret_cast<const float4*>(x + ((size_t)n * C_ + o) * H_ + hb);
  float4* op = reinterpret_cast<float4*>(out + ((size_t)n * C_ + o) * H_ + hb);
#pragma unroll
  for (int i4 = 0; i4 < 4; ++i4) {
    const float4 xv = xp[i4];
    float4 r;
    r.x = fmaxf(0.f, fmaf(a, tile[hb + i4 * 4 + 0][ol], c) + xv.x);
    r.y = fmaxf(0.f, fmaf(a, tile[hb + i4 * 4 + 1][ol], c) + xv.y);
    r.z = fmaxf(0.f, fmaf(a, tile[hb + i4 * 4 + 2][ol], c) + xv.z);
    r.w = fmaxf(0.f, fmaf(a, tile[hb + i4 * 4 + 3][ol], c) + xv.w);
    op[i4] = r;
  }
}

// ---------------------------------------------------------------------------
extern "C" void kernel_launch(void* const* d_in, const int* in_sizes, int n_in,
                              void* d_out, int out_size, void* d_ws, size_t ws_size,
                              hipStream_t stream) {
  const float* x  = (const float*)d_in[0];
  const float* w1 = (const float*)d_in[1];
  const float* g1 = (const float*)d_in[2];
  const float* b1 = (const float*)d_in[3];
  const float* w2 = (const float*)d_in[4];
  const float* g2 = (const float*)d_in[5];
  const float* b2 = (const float*)d_in[6];
  float* out = (float*)d_out;

  // workspace layout (needs ~117.6 MB)
  char* ws = (char*)d_ws;
  float* stats = (float*)ws;  // sum1, sq1, sum2, sq2, a1, c1, a2, c2
  float* sum1 = stats,        *sq1 = stats + 512;
  float* sum2 = stats + 1024, *sq2 = stats + 1536;
  float* a1 = stats + 2048, *c1 = stats + 2560;
  float* a2 = stats + 3072, *c2 = stats + 3584;
  const size_t MB = (size_t)1 << 20;
  __bf16* xT  = (__bf16*)(ws + 64 * 1024);
  __bf16* w1T = (__bf16*)(ws + 64 * 1024 + 16 * MB);
  __bf16* w2T = (__bf16*)(ws + 64 * 1024 + 48 * MB);
  __bf16* t1T = (__bf16*)(ws + 64 * 1024 + 80 * MB);
  __bf16* t2T = (__bf16*)(ws + 64 * 1024 + 96 * MB);

  hipMemsetAsync(stats, 0, 2048 * sizeof(float), stream);

  k_transpose<<<dim3(8, 256), 256, 0, stream>>>(x,  xT,  256, 512);
  k_transpose<<<dim3(8, 512), 256, 0, stream>>>(w1, w1T, 512, 512);
  k_transpose<<<dim3(8, 512), 256, 0, stream>>>(w2, w2T, 512, 512);

  k_gemm<false><<<dim3(8, 64), 256, 0, stream>>>(xT, w1T, t1T, nullptr, nullptr, sum1, sq1);
  k_bnfin<<<1, 512, 0, stream>>>(sum1, sq1, g1, b1, a1, c1, 1.f / 16384.f);
  k_gemm<true><<<dim3(8, 64), 256, 0, stream>>>(t1T, w2T, t2T, a1, c1, sum2, sq2);
  k_bnfin<<<1, 512, 0, stream>>>(sum2, sq2, g2, b2, a2, c2, 1.f / 16384.f);

  k_finalize<<<dim3(8, 256), 256, 0, stream>>>(t2T, x, a2, c2, out);
}

// Round 3
// 104.371 us; speedup vs baseline: 1.2786x; 1.2786x over previous
//
#include <hip/hip_runtime.h>

typedef float  f32x4  __attribute__((ext_vector_type(4)));
typedef __bf16 bf16x8 __attribute__((ext_vector_type(8)));
typedef __bf16 bf16x4 __attribute__((ext_vector_type(4)));
typedef __bf16 bf16x2 __attribute__((ext_vector_type(2)));

#define N_ 256
#define C_ 512
#define H_ 64

// ---------------------------------------------------------------------------
// Merged prep: transpose x,w1,w2 from (P, Q, 64) fp32 -> (64, P, Q) bf16,
// plus zero the BN stat accumulators (block (0,0)).
// ---------------------------------------------------------------------------
__global__ __launch_bounds__(256) void k_prep(const float* __restrict__ x,
                                              const float* __restrict__ w1,
                                              const float* __restrict__ w2,
                                              __bf16* __restrict__ xT,
                                              __bf16* __restrict__ w1T,
                                              __bf16* __restrict__ w2T,
                                              float* __restrict__ stats) {
  __shared__ float tile[64][65];
  const int by = blockIdx.y;
  const int t  = threadIdx.x;
  if (by == 0 && blockIdx.x == 0) {
#pragma unroll
    for (int i = 0; i < 8; ++i) stats[i * 256 + t] = 0.f;  // sum1,sq1,sum2,sq2
  }
  const float* src;
  __bf16* dst;
  int p, P;
  if (by < 256)      { src = x;  dst = xT;  p = by;       P = 256; }
  else if (by < 768) { src = w1; dst = w1T; p = by - 256; P = 512; }
  else               { src = w2; dst = w2T; p = by - 768; P = 512; }
  const int q0 = blockIdx.x * 64;
  const float* s = src + ((size_t)p * 512 + q0) * 64;
  const int a = t >> 4, b = t & 15;
#pragma unroll
  for (int j = 0; j < 4; ++j) {
    const int qq = j * 16 + a;
    const float4 v = *reinterpret_cast<const float4*>(s + qq * 64 + b * 4);
    tile[qq][b * 4 + 0] = v.x;
    tile[qq][b * 4 + 1] = v.y;
    tile[qq][b * 4 + 2] = v.z;
    tile[qq][b * 4 + 3] = v.w;
  }
  __syncthreads();
#pragma unroll
  for (int j = 0; j < 4; ++j) {
    const int hh = j * 16 + a;
    bf16x4 y;
#pragma unroll
    for (int e = 0; e < 4; ++e) y[e] = (__bf16)tile[b * 4 + e][hh];
    *reinterpret_cast<bf16x4*>(dst + ((size_t)hh * P + p) * 512 + q0 + b * 4) = y;
  }
}

// ---------------------------------------------------------------------------
// Batched NT GEMM: per h, C[256][512] = A[256][512] * B[512][512]^T  (bf16)
// 128x128 tile, 4 waves (2x2), BK=64, mfma_f32_16x16x32_bf16.
// XCD-aware swizzle: 512 blocks, each XCD owns 8 complete h slices.
// 2-phase double-buffered LDS staging (prefetch next K-tile before compute).
// LDS chunk-XOR swizzle via pre-swizzled global source (linear LDS dest).
// Epilogue: bf16 C + per-channel sum/sumsq atomics.
// BN_A: A gets y = relu(a1[k]*a + c1[k]) computed on the fly from sum1/sq1.
// ---------------------------------------------------------------------------
template <bool BN_A>
__global__ __launch_bounds__(256, 2) void k_gemm(
    const __bf16* __restrict__ A,   // (H, 256, 512)
    const __bf16* __restrict__ B,   // (H, 512, 512)
    __bf16* __restrict__ Co,        // (H, 256, 512)
    const float* __restrict__ sum_in, const float* __restrict__ sq_in,
    const float* __restrict__ g, const float* __restrict__ bb,
    float* __restrict__ sum_out, float* __restrict__ sq_out) {
  // bijective XCD swizzle: nwg=512, 64 per XCD chunk -> same-h tiles colocate
  const int wkid = (blockIdx.x & 7) * 64 + (blockIdx.x >> 3);
  const int h  = wkid >> 3;
  const int tm = (wkid >> 2) & 1, tn = wkid & 3;
  const int m0 = tm * 128, n0 = tn * 128;
  const __bf16* Ah = A + ((size_t)h * N_ + m0) * C_;
  const __bf16* Bh = B + ((size_t)h * C_ + n0) * C_;
  __shared__ __bf16 As[2][128 * 64];
  __shared__ __bf16 Bs[2][128 * 64];
  __shared__ float a_lds[512], c_lds[512];
  const int tid  = threadIdx.x;
  const int lane = tid & 63, wid = tid >> 6;
  const int wr = wid >> 1, wc = wid & 1;
  const int lrow8 = lane >> 3;
  const int swz   = (lane & 7) ^ lrow8;

  if (BN_A) {
#pragma unroll
    for (int ch = tid; ch < 512; ch += 256) {
      const float m    = sum_in[ch] * (1.f / 16384.f);
      const float var  = fmaxf(0.f, sq_in[ch] * (1.f / 16384.f) - m * m);
      const float aa   = g[ch] * rsqrtf(var + 1e-5f);
      a_lds[ch] = aa;
      c_lds[ch] = bb[ch] - m * aa;
    }
    __syncthreads();
  }

  auto stage_b = [&](int buf, int kt) {
#pragma unroll
    for (int i = 0; i < 4; ++i) {
      const int rbase = wid * 32 + i * 8;
      const __bf16* gb = Bh + (size_t)(rbase + lrow8) * C_ + kt * 64 + swz * 8;
      __builtin_amdgcn_global_load_lds(
          (const __attribute__((address_space(1))) void*)gb,
          (__attribute__((address_space(3))) void*)(&Bs[buf][rbase * 64]), 16, 0, 0);
    }
  };
  auto stage_a = [&](int buf, int kt) {
#pragma unroll
    for (int i = 0; i < 4; ++i) {
      const int rbase = wid * 32 + i * 8;
      const __bf16* ga = Ah + (size_t)(rbase + lrow8) * C_ + kt * 64 + swz * 8;
      __builtin_amdgcn_global_load_lds(
          (const __attribute__((address_space(1))) void*)ga,
          (__attribute__((address_space(3))) void*)(&As[buf][rbase * 64]), 16, 0, 0);
    }
  };
  const int lr32 = tid >> 3, cch = tid & 7;
  auto load_a = [&](bf16x8* v, int kt) {
#pragma unroll
    for (int i = 0; i < 4; ++i)
      v[i] = *reinterpret_cast<const bf16x8*>(
          Ah + (size_t)(i * 32 + lr32) * C_ + kt * 64 + cch * 8);
  };
  auto bn_write = [&](const bf16x8* v, int buf, int kt) {
    const int cg = kt * 64 + cch * 8;
    const f32x4 s0 = *reinterpret_cast<const f32x4*>(&a_lds[cg]);
    const f32x4 s1 = *reinterpret_cast<const f32x4*>(&a_lds[cg + 4]);
    const f32x4 h0 = *reinterpret_cast<const f32x4*>(&c_lds[cg]);
    const f32x4 h1 = *reinterpret_cast<const f32x4*>(&c_lds[cg + 4]);
#pragma unroll
    for (int i = 0; i < 4; ++i) {
      const int row = i * 32 + lr32;
      bf16x8 y;
#pragma unroll
      for (int e = 0; e < 4; ++e) {
        y[e]     = (__bf16)fmaxf(0.f, fmaf((float)v[i][e],     s0[e], h0[e]));
        y[e + 4] = (__bf16)fmaxf(0.f, fmaf((float)v[i][e + 4], s1[e], h1[e]));
      }
      const int boff = row * 128 + ((cch * 16) ^ ((row & 7) << 4));
      *reinterpret_cast<bf16x8*>(reinterpret_cast<char*>(&As[buf][0]) + boff) = y;
    }
  };

  f32x4 acc[4][4] = {};
  const int fr = lane & 15, kc = lane >> 4;
  auto compute = [&](int buf) {
#pragma unroll
    for (int kk = 0; kk < 2; ++kk) {
      bf16x8 af[4], bfq[4];
#pragma unroll
      for (int mf = 0; mf < 4; ++mf) {
        const int row  = wr * 64 + mf * 16 + fr;
        const int boff = row * 128 + (((kk * 64 + kc * 16)) ^ ((row & 7) << 4));
        af[mf] = *reinterpret_cast<const bf16x8*>(
            reinterpret_cast<const char*>(&As[buf][0]) + boff);
      }
#pragma unroll
      for (int nf = 0; nf < 4; ++nf) {
        const int row  = wc * 64 + nf * 16 + fr;
        const int boff = row * 128 + (((kk * 64 + kc * 16)) ^ ((row & 7) << 4));
        bfq[nf] = *reinterpret_cast<const bf16x8*>(
            reinterpret_cast<const char*>(&Bs[buf][0]) + boff);
      }
#pragma unroll
      for (int mf = 0; mf < 4; ++mf)
#pragma unroll
        for (int nf = 0; nf < 4; ++nf)
          acc[mf][nf] = __builtin_amdgcn_mfma_f32_16x16x32_bf16(af[mf], bfq[nf], acc[mf][nf], 0, 0, 0);
    }
  };

  // prologue: stage tile 0 into buf 0
  if (BN_A) {
    bf16x8 v0[4];
    load_a(v0, 0);
    bn_write(v0, 0, 0);
  } else {
    stage_a(0, 0);
  }
  stage_b(0, 0);
  __syncthreads();

  int buf = 0;
  for (int kt = 0; kt < 8; ++kt) {
    bf16x8 vn[4];
    if (kt < 7) {
      stage_b(buf ^ 1, kt + 1);
      if (!BN_A) stage_a(buf ^ 1, kt + 1);
      else       load_a(vn, kt + 1);
    }
    compute(buf);
    if (BN_A && kt < 7) bn_write(vn, buf ^ 1, kt + 1);
    __syncthreads();
    buf ^= 1;
  }

  // epilogue: C/D layout col=lane&15, row=(lane>>4)*4+j
  const int rq = (lane >> 4) * 4;
  __bf16* Ch = Co + (size_t)h * N_ * C_;
#pragma unroll
  for (int nf = 0; nf < 4; ++nf) {
    const int oc = n0 + wc * 64 + nf * 16 + fr;
    float s = 0.f, s2 = 0.f;
#pragma unroll
    for (int mf = 0; mf < 4; ++mf) {
      const int rb = m0 + wr * 64 + mf * 16 + rq;
      f32x4 v = acc[mf][nf];
#pragma unroll
      for (int j = 0; j < 4; ++j) {
        const float f = v[j];
        Ch[(size_t)(rb + j) * C_ + oc] = (__bf16)f;
        s += f;
        s2 += f * f;
      }
    }
    s  += __shfl_xor(s, 16);  s  += __shfl_xor(s, 32);
    s2 += __shfl_xor(s2, 16); s2 += __shfl_xor(s2, 32);
    if (lane < 16) {
      atomicAdd(&sum_out[oc], s);
      atomicAdd(&sq_out[oc], s2);
    }
  }
}

// ---------------------------------------------------------------------------
// Final: out[n][o][h] = relu(a2[o]*t2[h][n][o] + c2[o] + x[n][o][h])
// a2/c2 computed per block (64 channels) from sum2/sq2.
// ---------------------------------------------------------------------------
__global__ __launch_bounds__(256) void k_finalize(const __bf16* __restrict__ t2,
                                                  const float* __restrict__ x,
                                                  const float* __restrict__ sum2,
                                                  const float* __restrict__ sq2,
                                                  const float* __restrict__ g2,
                                                  const float* __restrict__ b2,
                                                  float* __restrict__ out) {
  __shared__ float tile[64][65];
  __shared__ float a2s[64], c2s[64];
  const int n  = blockIdx.y;
  const int o0 = blockIdx.x * 64;
  const int t  = threadIdx.x;
  if (t < 64) {
    const int o = o0 + t;
    const float m    = sum2[o] * (1.f / 16384.f);
    const float var  = fmaxf(0.f, sq2[o] * (1.f / 16384.f) - m * m);
    const float a    = g2[o] * rsqrtf(var + 1e-5f);
    a2s[t] = a;
    c2s[t] = b2[o] - m * a;
  }
#pragma unroll
  for (int j = 0; j < 8; ++j) {
    const int hh = j * 8 + (t >> 5);
    const int ol = (t & 31) * 2;
    bf16x2 v = *reinterpret_cast<const bf16x2*>(t2 + ((size_t)hh * N_ + n) * C_ + o0 + ol);
    tile[hh][ol]     = (float)v[0];
    tile[hh][ol + 1] = (float)v[1];
  }
  __syncthreads();
  const int ol = t >> 2;
  const int hb = (t & 3) * 16;
  const int o  = o0 + ol;
  const float a = a2s[ol], c = c2s[ol];
  const float4* xp = reinterpret_cast<const float4*>(x + ((size_t)n * C_ + o) * H_ + hb);
  float4* op = reinterpret_cast<float4*>(out + ((size_t)n * C_ + o) * H_ + hb);
#pragma unroll
  for (int i4 = 0; i4 < 4; ++i4) {
    const float4 xv = xp[i4];
    float4 r;
    r.x = fmaxf(0.f, fmaf(a, tile[hb + i4 * 4 + 0][ol], c) + xv.x);
    r.y = fmaxf(0.f, fmaf(a, tile[hb + i4 * 4 + 1][ol], c) + xv.y);
    r.z = fmaxf(0.f, fmaf(a, tile[hb + i4 * 4 + 2][ol], c) + xv.z);
    r.w = fmaxf(0.f, fmaf(a, tile[hb + i4 * 4 + 3][ol], c) + xv.w);
    op[i4] = r;
  }
}

// ---------------------------------------------------------------------------
extern "C" void kernel_launch(void* const* d_in, const int* in_sizes, int n_in,
                              void* d_out, int out_size, void* d_ws, size_t ws_size,
                              hipStream_t stream) {
  const float* x  = (const float*)d_in[0];
  const float* w1 = (const float*)d_in[1];
  const float* g1 = (const float*)d_in[2];
  const float* b1 = (const float*)d_in[3];
  const float* w2 = (const float*)d_in[4];
  const float* g2 = (const float*)d_in[5];
  const float* b2 = (const float*)d_in[6];
  float* out = (float*)d_out;

  char* ws = (char*)d_ws;
  float* stats = (float*)ws;  // sum1, sq1, sum2, sq2
  float* sum1 = stats,        *sq1 = stats + 512;
  float* sum2 = stats + 1024, *sq2 = stats + 1536;
  const size_t MB = (size_t)1 << 20;
  __bf16* xT  = (__bf16*)(ws + 64 * 1024);
  __bf16* w1T = (__bf16*)(ws + 64 * 1024 + 16 * MB);
  __bf16* w2T = (__bf16*)(ws + 64 * 1024 + 48 * MB);
  __bf16* t1T = (__bf16*)(ws + 64 * 1024 + 80 * MB);
  __bf16* t2T = (__bf16*)(ws + 64 * 1024 + 96 * MB);

  k_prep<<<dim3(8, 1280), 256, 0, stream>>>(x, w1, w2, xT, w1T, w2T, stats);

  k_gemm<false><<<512, 256, 0, stream>>>(xT, w1T, t1T, nullptr, nullptr,
                                         nullptr, nullptr, sum1, sq1);
  k_gemm<true><<<512, 256, 0, stream>>>(t1T, w2T, t2T, sum1, sq1, g1, b1,
                                        sum2, sq2);

  k_finalize<<<dim3(8, 256), 256, 0, stream>>>(t2T, x, sum2, sq2, g2, b2, out);
}